// Round 6
// baseline (264.650 us; speedup 1.0000x reference)
//
#include <hip/hip_runtime.h>
#include <hip/hip_bf16.h>

typedef __attribute__((ext_vector_type(4))) float f32x4;
typedef __attribute__((ext_vector_type(8))) short bfx8;   // 8 bf16 = 4 VGPRs (MFMA A/B frag)

#define K_DIM 1024
#define N_DIM 1024

__device__ __forceinline__ ushort f2bf(float f) {
    uint u = __float_as_uint(f);
    u += 0x7fffu + ((u >> 16) & 1u);     // round-to-nearest-even
    return (ushort)(u >> 16);
}

// async global->LDS, 16B per lane. LDS dest must be wave-uniform base (lane*16 implicit).
__device__ __forceinline__ void gll16(const ushort* g, ushort* l) {
    __builtin_amdgcn_global_load_lds(
        (const __attribute__((address_space(1))) uint*)g,
        (__attribute__((address_space(3))) uint*)l,
        16, 0, 0);
}

// VALU-only reduce step: x + dpp_perm(x). CTRL must be a compile-time constant:
// 0xB1=quad_perm[1,0,3,2](xor1), 0x4E=quad_perm[2,3,0,1](xor2),
// 0x124=row_ror:4, 0x128=row_ror:8 (row = 16 lanes).
template<int CTRL>
__device__ __forceinline__ float dpp_add(float x) {
    int yi = __builtin_amdgcn_update_dpp(0, __float_as_int(x), CTRL, 0xf, 0xf, true);
    return x + __int_as_float(yi);
}

// ---------------- f32 -> bf16 conversion of the 4 weights ----------------
__global__ __launch_bounds__(256) void cvt_w(
    const float* __restrict__ wq, const float* __restrict__ wk,
    const float* __restrict__ wv, const float* __restrict__ wo,
    ushort* __restrict__ ws)
{
    const int W4 = 1 << 18;   // 1024*1024/4 float4 units per weight
    const int total = 4*W4;
    ushort4* dst4 = reinterpret_cast<ushort4*>(ws);
    for (int u = blockIdx.x*blockDim.x + threadIdx.x; u < total; u += gridDim.x*blockDim.x) {
        int op = u >> 18;
        int local = u & (W4-1);
        const float* src = op==0 ? wq : (op==1 ? wk : (op==2 ? wv : wo));
        float4 f = reinterpret_cast<const float4*>(src)[local];
        ushort4 o;
        o.x = f2bf(f.x); o.y = f2bf(f.y); o.z = f2bf(f.z); o.w = f2bf(f.w);
        dst4[u] = o;
    }
}

// ---------------- GEMM body: C[m][n] = sum_k A[m][k] * W[n][k] ----
// 128x128 tile, BK=64, 4 waves (2x2 of 64x64), 16x16x32 bf16 MFMA.
// B (weights) staged via global_load_lds w16 with pre-swizzled source.
// MODE 0/1: A is f32 global (inputs), converted to bf16 during reg-staging.
// MODE 2:   A is bf16 (AO), staged via global_load_lds.
// MODE 0: out bf16 [B][H][S][D]   (Q/K projection)
// MODE 1: out bf16 [B][H][D][S]   (V projection, transposed for PV reads)
// MODE 2: out f32  [M][N]         (final output -> d_out, reference dtype f32)
template<int MODE>
__device__ __forceinline__ void gemm_body(
    const float* __restrict__ Af, const ushort* __restrict__ Ab,
    const ushort* __restrict__ Bw,
    ushort* __restrict__ C, float* __restrict__ Cf,
    int blk, ushort* As, ushort* Bs)
{
    const int tid  = threadIdx.x;
    const int lane = tid & 63;
    const int wave = tid >> 6;
    const int tn = blk & 7;     // N/128 = 8
    const int tm = blk >> 3;    // M/128 = 32
    const int wr = wave >> 1, wc = wave & 1;

    // per-lane pre-swizzled source offsets for gll staging (4 x 16B units per tile)
    int goff[4];
    #pragma unroll
    for (int t = 0; t < 4; ++t) {
        int u = wave*256 + t*64 + lane;          // 1024 units per 128x64 tile
        int row = u >> 3;
        int col = (u & 7) ^ (row & 7);           // inverse swizzle on source
        goff[t] = row * K_DIM + col * 8;
    }
    const ushort* Bbase  = Bw + (size_t)tn * 128 * K_DIM;
    const float*  Afbase = (MODE < 2) ? Af + (size_t)tm * 128 * K_DIM : nullptr;
    const ushort* Abbase = (MODE == 2) ? Ab + (size_t)tm * 128 * K_DIM : nullptr;

    f32x4 acc[4][4];
    #pragma unroll
    for (int a = 0; a < 4; ++a)
        #pragma unroll
        for (int b2 = 0; b2 < 4; ++b2)
            acc[a][b2] = (f32x4){0.f, 0.f, 0.f, 0.f};

    for (int k0 = 0; k0 < K_DIM; k0 += 64) {
        __syncthreads();   // prior compute done reading LDS
        #pragma unroll
        for (int t = 0; t < 4; ++t)
            gll16(Bbase + k0 + goff[t], Bs + (wave*256 + t*64)*8);
        if constexpr (MODE == 2) {
            #pragma unroll
            for (int t = 0; t < 4; ++t)
                gll16(Abbase + k0 + goff[t], As + (wave*256 + t*64)*8);
        } else {
            // reg-staged A with fused f32->bf16 conversion, swizzled ds_write
            #pragma unroll
            for (int t = 0; t < 4; ++t) {
                int u = tid + t*256;
                int row = u >> 3, col = u & 7;
                const float* s = Afbase + (size_t)row*K_DIM + k0 + col*8;
                float4 f0 = *reinterpret_cast<const float4*>(s);
                float4 f1 = *reinterpret_cast<const float4*>(s + 4);
                ushort4 lo, hi;
                lo.x = f2bf(f0.x); lo.y = f2bf(f0.y); lo.z = f2bf(f0.z); lo.w = f2bf(f0.w);
                hi.x = f2bf(f1.x); hi.y = f2bf(f1.y); hi.z = f2bf(f1.z); hi.w = f2bf(f1.w);
                ushort* d = &As[row*64 + (col ^ (row & 7))*8];
                *reinterpret_cast<ushort4*>(d)     = lo;
                *reinterpret_cast<ushort4*>(d + 4) = hi;
            }
        }
        __syncthreads();   // drains vmcnt+lgkm -> tiles ready
        #pragma unroll
        for (int kk = 0; kk < 2; ++kk) {
            bfx8 af[4], bfr[4];
            #pragma unroll
            for (int mi = 0; mi < 4; ++mi) {
                int row  = wr*64 + mi*16 + (lane & 15);
                int unit = kk*4 + (lane >> 4);
                af[mi] = *reinterpret_cast<const bfx8*>(&As[row*64 + (unit ^ (row & 7))*8]);
            }
            #pragma unroll
            for (int ni = 0; ni < 4; ++ni) {
                int row  = wc*64 + ni*16 + (lane & 15);
                int unit = kk*4 + (lane >> 4);
                bfr[ni] = *reinterpret_cast<const bfx8*>(&Bs[row*64 + (unit ^ (row & 7))*8]);
            }
            #pragma unroll
            for (int mi = 0; mi < 4; ++mi)
                #pragma unroll
                for (int ni = 0; ni < 4; ++ni)
                    acc[mi][ni] = __builtin_amdgcn_mfma_f32_16x16x32_bf16(af[mi], bfr[ni], acc[mi][ni], 0, 0, 0);
        }
    }
    // epilogue: D layout col = lane&15, row = (lane>>4)*4 + i
    #pragma unroll
    for (int mi = 0; mi < 4; ++mi)
      #pragma unroll
      for (int ni = 0; ni < 4; ++ni)
        #pragma unroll
        for (int i = 0; i < 4; ++i) {
            int gr = tm*128 + wr*64 + mi*16 + (lane >> 4)*4 + i;   // m: b*2048+s
            int gc = tn*128 + wc*64 + ni*16 + (lane & 15);         // n: h*64+d
            if constexpr (MODE == 0) {
                int b = gr >> 11, s = gr & 2047, h = gc >> 6, d = gc & 63;
                C[(((size_t)(b*16 + h))*2048 + s)*64 + d] = f2bf(acc[mi][ni][i]);
            } else if constexpr (MODE == 1) {
                int b = gr >> 11, s = gr & 2047, h = gc >> 6, d = gc & 63;
                C[(((size_t)(b*16 + h))*64 + d)*2048 + s] = f2bf(acc[mi][ni][i]);
            } else {
                Cf[(size_t)gr*N_DIM + gc] = acc[mi][ni][i];
            }
        }
}

__global__ __launch_bounds__(256) void proj_kernel(
    const float* __restrict__ q, const float* __restrict__ k, const float* __restrict__ v,
    const ushort* __restrict__ wqb, const ushort* __restrict__ wkb, const ushort* __restrict__ wvb,
    ushort* __restrict__ Qp, ushort* __restrict__ Kp, ushort* __restrict__ Vt)
{
    __shared__ ushort As[128*64];
    __shared__ ushort Bs[128*64];
    int op = blockIdx.y;
    if (op == 0)      gemm_body<0>(q, nullptr, wqb, Qp, nullptr, blockIdx.x, As, Bs);
    else if (op == 1) gemm_body<0>(k, nullptr, wkb, Kp, nullptr, blockIdx.x, As, Bs);
    else              gemm_body<1>(v, nullptr, wvb, Vt, nullptr, blockIdx.x, As, Bs);
}

__global__ __launch_bounds__(256) void outproj_kernel(
    const ushort* __restrict__ AO, const ushort* __restrict__ wob, float* __restrict__ out)
{
    __shared__ ushort As[128*64];
    __shared__ ushort Bs[128*64];
    gemm_body<2>(nullptr, AO, wob, nullptr, out, blockIdx.x, As, Bs);
}

// ---------------- block-sparse attention ----------------
// grid: b(2)*h(16)*rpair(16) = 512 blocks, 512 threads (8 waves).
// Waves 0-3 own r0's 16-row strips, waves 4-7 own r1's. One c-band union
// [r0-15, r1+15] (<=33 tiles) serves both r's -> staging/barriers halve.
// Double-buffered K/V via global_load_lds; Q/P share one wave-private buffer;
// one barrier per phase; per-pair softmax with DPP rotate-reduce.
__global__ __launch_bounds__(512) void attn_kernel(
    const ushort* __restrict__ Qp, const ushort* __restrict__ Kp,
    const ushort* __restrict__ Vt, ushort* __restrict__ AO)
{
    const int blk = blockIdx.x;
    const int g = blk & 15;              // r-pair index
    const int h = (blk >> 4) & 15;
    const int b = blk >> 8;
    const int r0 = g << 1;
    const int tid  = threadIdx.x;
    const int lane = tid & 63;
    const int wave = tid >> 6;           // 0..7
    const int rw = r0 + (wave >> 2);     // this wave's r-tile

    __shared__ ushort Ks[2][4096];
    __shared__ ushort Vs[2][4096];
    __shared__ ushort QPs[8192];         // 128 rows x 64: Q (prologue) then P (wave-private rows)

    const ushort* Qb = Qp + (size_t)(b*16 + h) * 2048 * 64;
    const ushort* Kb = Kp + (size_t)(b*16 + h) * 2048 * 64;
    const ushort* Vb = Vt + (size_t)(b*16 + h) * 64 * 2048;

    // K/V per-lane pre-swizzled source offsets (1 unit per lane per tile: 512 units, 512 threads)
    const int krow = tid >> 3;
    const int kcol = (tid & 7) ^ (krow & 7);
    const int koff = krow*64   + kcol*8;
    const int voff = krow*2048 + kcol*8;

    int clo = r0 - 15; if (clo < 0) clo = 0;
    int chi = r0 + 16; if (chi > 31) chi = 31;   // r1+15

    // prologue: Q (2 r-tiles, 2 units/wave-lane) + first K/V tile
    #pragma unroll
    for (int t = 0; t < 2; ++t) {
        int u = wave*128 + t*64 + lane;
        int row = u >> 3;
        int col = (u & 7) ^ (row & 7);
        gll16(Qb + (size_t)(r0*64 + row)*64 + col*8, QPs + (wave*128 + t*64)*8);
    }
    gll16(Kb + (size_t)clo*4096 + koff, &Ks[0][wave*64*8]);
    gll16(Vb + (size_t)clo*64   + voff, &Vs[0][wave*64*8]);
    __syncthreads();   // drains vmcnt(0): Q + tile clo in LDS

    // hoist Q fragments (loop-invariant, wave-private rows)
    bfx8 qf[2];
    #pragma unroll
    for (int kk = 0; kk < 2; ++kk) {
        int arow = wave*16 + (lane & 15);
        int unit = kk*4 + (lane >> 4);
        qf[kk] = *reinterpret_cast<const bfx8*>(&QPs[arow*64 + (unit ^ (arow & 7))*8]);
    }

    f32x4 acc_o[4];
    #pragma unroll
    for (int n = 0; n < 4; ++n) acc_o[n] = (f32x4){0.f,0.f,0.f,0.f};

    const float SC = 0.125f * 1.44269504f;    // scale folded with log2(e)
    int cur = 0;
    for (int c = clo; c <= chi; ++c) {
        // prefetch next K/V into the other buffer (flies during compute)
        if (c < chi) {
            gll16(Kb + (size_t)(c+1)*4096 + koff, &Ks[cur^1][wave*64*8]);
            gll16(Vb + (size_t)(c+1)*64   + voff, &Vs[cur^1][wave*64*8]);
        }

        if (c >= rw - 15 && c <= rw + 15) {   // this wave's band (guard has no barrier)
            // QK^T: wave's 16-row strip x 64 keys
            f32x4 sc[4];
            #pragma unroll
            for (int n = 0; n < 4; ++n) sc[n] = (f32x4){0.f,0.f,0.f,0.f};
            #pragma unroll
            for (int kk = 0; kk < 2; ++kk) {
                #pragma unroll
                for (int n = 0; n < 4; ++n) {
                    int brow = n*16 + (lane & 15);
                    int unit = kk*4 + (lane >> 4);
                    bfx8 kf = *reinterpret_cast<const bfx8*>(&Ks[cur][brow*64 + (unit ^ (brow & 7))*8]);
                    sc[n] = __builtin_amdgcn_mfma_f32_16x16x32_bf16(qf[kk], kf, sc[n], 0,0,0);
                }
            }

            // per-pair softmax, no max-subtract; VALU-only DPP reduce over 16 lanes
            float pn[4][4]; float inv[4];
            #pragma unroll
            for (int i = 0; i < 4; ++i) {
                float ssum = 0.f;
                #pragma unroll
                for (int n = 0; n < 4; ++n) { float e = exp2f(sc[n][i]*SC); pn[n][i] = e; ssum += e; }
                ssum = dpp_add<0xB1>(ssum);     // quad_perm [1,0,3,2]
                ssum = dpp_add<0x4E>(ssum);     // quad_perm [2,3,0,1]
                ssum = dpp_add<0x124>(ssum);    // row_ror:4
                ssum = dpp_add<0x128>(ssum);    // row_ror:8
                inv[i] = __builtin_amdgcn_rcpf(ssum);
            }
            // write normalized P (bf16, swizzled) — wave-private rows, no barrier needed
            #pragma unroll
            for (int n = 0; n < 4; ++n)
                #pragma unroll
                for (int i = 0; i < 4; ++i) {
                    int row  = wave*16 + (lane >> 4)*4 + i;
                    int colv = n*16 + (lane & 15);
                    QPs[row*64 + ((colv >> 3) ^ (row & 7))*8 + (colv & 7)] = f2bf(pn[n][i]*inv[i]);
                }

            // O += P * V
            #pragma unroll
            for (int kk = 0; kk < 2; ++kk) {
                int arow = wave*16 + (lane & 15);
                int unit = kk*4 + (lane >> 4);
                bfx8 pf = *reinterpret_cast<const bfx8*>(&QPs[arow*64 + (unit ^ (arow & 7))*8]);
                #pragma unroll
                for (int n = 0; n < 4; ++n) {
                    int brow = n*16 + (lane & 15);   // d
                    bfx8 vf = *reinterpret_cast<const bfx8*>(&Vs[cur][brow*64 + (unit ^ (brow & 7))*8]);
                    acc_o[n] = __builtin_amdgcn_mfma_f32_16x16x32_bf16(pf, vf, acc_o[n], 0,0,0);
                }
            }
        }

        __syncthreads();   // drains vmcnt(0): prefetch landed; all reads of cur done
        cur ^= 1;
    }

    // write O strip to AO [B][S][E] (bf16 workspace), e = h*64 + d
    #pragma unroll
    for (int n = 0; n < 4; ++n)
        #pragma unroll
        for (int i = 0; i < 4; ++i) {
            int qrow = r0*64 + wave*16 + (lane >> 4)*4 + i;
            int e    = h*64 + n*16 + (lane & 15);
            AO[((size_t)b*2048 + qrow)*1024 + e] = f2bf(acc_o[n][i]);
        }
}

extern "C" void kernel_launch(void* const* d_in, const int* in_sizes, int n_in,
                              void* d_out, int out_size, void* d_ws, size_t ws_size,
                              hipStream_t stream)
{
    (void)in_sizes; (void)n_in; (void)out_size; (void)ws_size;
    const float* q  = (const float*)d_in[0];
    const float* k  = (const float*)d_in[1];
    const float* v  = (const float*)d_in[2];
    const float* wq = (const float*)d_in[3];
    const float* wk = (const float*)d_in[4];
    const float* wv = (const float*)d_in[5];
    const float* wo = (const float*)d_in[6];

    ushort* ws = (ushort*)d_ws;
    const size_t IN_E = 4096ull * 1024ull;   // 4,194,304 elems
    const size_t W_E  = 1024ull * 1024ull;   // 1,048,576 elems
    ushort* wqb = ws;                  // bf16 weights
    ushort* wkb = wqb + W_E;
    ushort* wvb = wkb + W_E;
    ushort* wob = wvb + W_E;
    ushort* Qp  = wob + W_E;           // [B][H][S][D]
    ushort* Kp  = Qp + IN_E;           // [B][H][S][D]
    ushort* Vt  = Kp + IN_E;           // [B][H][D][S]
    ushort* AO  = Vt + IN_E;           // [B][S][E]
    // total workspace: 4*W_E + 4*IN_E = 20,971,520 ushorts = 40 MiB

    cvt_w<<<1024, 256, 0, stream>>>(wq, wk, wv, wo, ws);
    proj_kernel<<<dim3(256, 3), 256, 0, stream>>>(q, k, v, wqb, wkb, wvb, Qp, Kp, Vt);
    attn_kernel<<<512, 512, 0, stream>>>(Qp, Kp, Vt, AO);
    outproj_kernel<<<256, 256, 0, stream>>>(AO, wob, (float*)d_out);
}

// Round 9
// 251.834 us; speedup vs baseline: 1.0509x; 1.0509x over previous
//
#include <hip/hip_runtime.h>
#include <hip/hip_bf16.h>

typedef __attribute__((ext_vector_type(4))) float f32x4;
typedef __attribute__((ext_vector_type(8))) short bfx8;   // 8 bf16 = 4 VGPRs (MFMA A/B frag)

#define K_DIM 1024
#define N_DIM 1024

__device__ __forceinline__ ushort f2bf(float f) {
    uint u = __float_as_uint(f);
    u += 0x7fffu + ((u >> 16) & 1u);     // round-to-nearest-even
    return (ushort)(u >> 16);
}

// pack 2 f32 -> 1 uint of 2 bf16 via hardware v_cvt_pk_bf16_f32 (compiler-selected);
// memcpy reinterpret (bit_cast rejects __hip_bfloat162: not trivially copyable)
__device__ __forceinline__ uint pk2bf(float lo, float hi) {
    __hip_bfloat162 h = __float22bfloat162_rn(float2{lo, hi});
    uint r;
    __builtin_memcpy(&r, &h, 4);
    return r;
}

// async global->LDS, 16B per lane. LDS dest must be wave-uniform base (lane*16 implicit).
__device__ __forceinline__ void gll16(const ushort* g, ushort* l) {
    __builtin_amdgcn_global_load_lds(
        (const __attribute__((address_space(1))) uint*)g,
        (__attribute__((address_space(3))) uint*)l,
        16, 0, 0);
}

// VALU-only reduce step: x + dpp_perm(x). CTRL must be a compile-time constant:
// 0xB1=quad_perm[1,0,3,2](xor1), 0x4E=quad_perm[2,3,0,1](xor2),
// 0x124=row_ror:4, 0x128=row_ror:8 (row = 16 lanes).
template<int CTRL>
__device__ __forceinline__ float dpp_add(float x) {
    int yi = __builtin_amdgcn_update_dpp(0, __float_as_int(x), CTRL, 0xf, 0xf, true);
    return x + __int_as_float(yi);
}

// ---------------- f32 -> bf16 conversion of the 4 weights ----------------
__global__ __launch_bounds__(256) void cvt_w(
    const float* __restrict__ wq, const float* __restrict__ wk,
    const float* __restrict__ wv, const float* __restrict__ wo,
    ushort* __restrict__ ws)
{
    const int W4 = 1 << 18;   // 1024*1024/4 float4 units per weight
    const int total = 4*W4;
    ushort4* dst4 = reinterpret_cast<ushort4*>(ws);
    for (int u = blockIdx.x*blockDim.x + threadIdx.x; u < total; u += gridDim.x*blockDim.x) {
        int op = u >> 18;
        int local = u & (W4-1);
        const float* src = op==0 ? wq : (op==1 ? wk : (op==2 ? wv : wo));
        float4 f = reinterpret_cast<const float4*>(src)[local];
        ushort4 o;
        o.x = f2bf(f.x); o.y = f2bf(f.y); o.z = f2bf(f.z); o.w = f2bf(f.w);
        dst4[u] = o;
    }
}

// ---------------- GEMM body: C[m][n] = sum_k A[m][k] * W[n][k] ----
// 128x128 tile, BK=64, 4 waves (2x2 of 64x64), 16x16x32 bf16 MFMA.
// B (weights) staged via global_load_lds w16 with pre-swizzled source.
// MODE 0/1: A is f32 global (inputs), converted to bf16 (cvt_pk) during reg-staging.
// MODE 2:   A is bf16 (AO), staged via global_load_lds.
// MODE 0: out bf16 [B][H][S][D]   (Q/K projection)
// MODE 1: out bf16 [B][H][D][S]   (V projection, transposed for PV reads)
// MODE 2: out f32  [M][N]         (final output -> d_out, reference dtype f32)
template<int MODE>
__device__ __forceinline__ void gemm_body(
    const float* __restrict__ Af, const ushort* __restrict__ Ab,
    const ushort* __restrict__ Bw,
    ushort* __restrict__ C, float* __restrict__ Cf,
    int blk, ushort* As, ushort* Bs)
{
    const int tid  = threadIdx.x;
    const int lane = tid & 63;
    const int wave = tid >> 6;
    const int tn = blk & 7;     // N/128 = 8
    const int tm = blk >> 3;    // M/128 = 32
    const int wr = wave >> 1, wc = wave & 1;

    // per-lane pre-swizzled source offsets for gll staging (4 x 16B units per tile)
    int goff[4];
    #pragma unroll
    for (int t = 0; t < 4; ++t) {
        int u = wave*256 + t*64 + lane;          // 1024 units per 128x64 tile
        int row = u >> 3;
        int col = (u & 7) ^ (row & 7);           // inverse swizzle on source
        goff[t] = row * K_DIM + col * 8;
    }
    const ushort* Bbase  = Bw + (size_t)tn * 128 * K_DIM;
    const float*  Afbase = (MODE < 2) ? Af + (size_t)tm * 128 * K_DIM : nullptr;
    const ushort* Abbase = (MODE == 2) ? Ab + (size_t)tm * 128 * K_DIM : nullptr;

    f32x4 acc[4][4];
    #pragma unroll
    for (int a = 0; a < 4; ++a)
        #pragma unroll
        for (int b2 = 0; b2 < 4; ++b2)
            acc[a][b2] = (f32x4){0.f, 0.f, 0.f, 0.f};

    for (int k0 = 0; k0 < K_DIM; k0 += 64) {
        __syncthreads();   // prior compute done reading LDS
        #pragma unroll
        for (int t = 0; t < 4; ++t)
            gll16(Bbase + k0 + goff[t], Bs + (wave*256 + t*64)*8);
        if constexpr (MODE == 2) {
            #pragma unroll
            for (int t = 0; t < 4; ++t)
                gll16(Abbase + k0 + goff[t], As + (wave*256 + t*64)*8);
        } else {
            // reg-staged A with fused f32->bf16 (v_cvt_pk), one 16B swizzled ds_write
            #pragma unroll
            for (int t = 0; t < 4; ++t) {
                int u = tid + t*256;
                int row = u >> 3, col = u & 7;
                const float* s = Afbase + (size_t)row*K_DIM + k0 + col*8;
                float4 f0 = *reinterpret_cast<const float4*>(s);
                float4 f1 = *reinterpret_cast<const float4*>(s + 4);
                uint4 packed;
                packed.x = pk2bf(f0.x, f0.y);
                packed.y = pk2bf(f0.z, f0.w);
                packed.z = pk2bf(f1.x, f1.y);
                packed.w = pk2bf(f1.z, f1.w);
                *reinterpret_cast<uint4*>(&As[row*64 + (col ^ (row & 7))*8]) = packed;
            }
        }
        __syncthreads();   // drains vmcnt+lgkm -> tiles ready
        #pragma unroll
        for (int kk = 0; kk < 2; ++kk) {
            bfx8 af[4], bfr[4];
            #pragma unroll
            for (int mi = 0; mi < 4; ++mi) {
                int row  = wr*64 + mi*16 + (lane & 15);
                int unit = kk*4 + (lane >> 4);
                af[mi] = *reinterpret_cast<const bfx8*>(&As[row*64 + (unit ^ (row & 7))*8]);
            }
            #pragma unroll
            for (int ni = 0; ni < 4; ++ni) {
                int row  = wc*64 + ni*16 + (lane & 15);
                int unit = kk*4 + (lane >> 4);
                bfr[ni] = *reinterpret_cast<const bfx8*>(&Bs[row*64 + (unit ^ (row & 7))*8]);
            }
            #pragma unroll
            for (int mi = 0; mi < 4; ++mi)
                #pragma unroll
                for (int ni = 0; ni < 4; ++ni)
                    acc[mi][ni] = __builtin_amdgcn_mfma_f32_16x16x32_bf16(af[mi], bfr[ni], acc[mi][ni], 0, 0, 0);
        }
    }
    // epilogue: D layout col = lane&15, row = (lane>>4)*4 + i
    #pragma unroll
    for (int mi = 0; mi < 4; ++mi)
      #pragma unroll
      for (int ni = 0; ni < 4; ++ni)
        #pragma unroll
        for (int i = 0; i < 4; ++i) {
            int gr = tm*128 + wr*64 + mi*16 + (lane >> 4)*4 + i;   // m: b*2048+s
            int gc = tn*128 + wc*64 + ni*16 + (lane & 15);         // n: h*64+d
            if constexpr (MODE == 0) {
                int b = gr >> 11, s = gr & 2047, h = gc >> 6, d = gc & 63;
                C[(((size_t)(b*16 + h))*2048 + s)*64 + d] = f2bf(acc[mi][ni][i]);
            } else if constexpr (MODE == 1) {
                int b = gr >> 11, s = gr & 2047, h = gc >> 6, d = gc & 63;
                C[(((size_t)(b*16 + h))*64 + d)*2048 + s] = f2bf(acc[mi][ni][i]);
            } else {
                Cf[(size_t)gr*N_DIM + gc] = acc[mi][ni][i];
            }
        }
}

// 1D grid 768 = 3 ops x 256 tiles; XCD swizzle: 96 consecutive wgid per XCD so
// the 8 tn-blocks sharing an A-panel hit the same XCD's L2.
__global__ __launch_bounds__(256) void proj_kernel(
    const float* __restrict__ q, const float* __restrict__ k, const float* __restrict__ v,
    const ushort* __restrict__ wqb, const ushort* __restrict__ wkb, const ushort* __restrict__ wvb,
    ushort* __restrict__ Qp, ushort* __restrict__ Kp, ushort* __restrict__ Vt)
{
    __shared__ ushort As[128*64];
    __shared__ ushort Bs[128*64];
    int wgid = (blockIdx.x & 7) * 96 + (blockIdx.x >> 3);   // 768 = 8*96, bijective
    int op = wgid >> 8;
    int t  = wgid & 255;
    if (op == 0)      gemm_body<0>(q, nullptr, wqb, Qp, nullptr, t, As, Bs);
    else if (op == 1) gemm_body<0>(k, nullptr, wkb, Kp, nullptr, t, As, Bs);
    else              gemm_body<1>(v, nullptr, wvb, Vt, nullptr, t, As, Bs);
}

__global__ __launch_bounds__(256) void outproj_kernel(
    const ushort* __restrict__ AO, const ushort* __restrict__ wob, float* __restrict__ out)
{
    __shared__ ushort As[128*64];
    __shared__ ushort Bs[128*64];
    int wgid = (blockIdx.x & 7) * 32 + (blockIdx.x >> 3);   // 256 = 8*32, bijective
    gemm_body<2>(nullptr, AO, wob, nullptr, out, wgid, As, Bs);
}

// ---------------- block-sparse attention ----------------
// grid: b(2)*h(16)*rpair(16) = 512 blocks, 512 threads (8 waves).
// XCD swizzle: 64 consecutive wgid per XCD = 4 full (b,h) groups -> K/V (1MB)
// resident in that XCD's L2 across its 16 r-pair blocks.
// Waves 0-3 own r0's 16-row strips, waves 4-7 own r1's. One c-band union
// [r0-15, r1+15] (<=33 tiles) serves both r's. Double-buffered K/V via
// global_load_lds; Q/P share one wave-private buffer; one barrier per phase;
// per-pair softmax with DPP rotate-reduce.
__global__ __launch_bounds__(512) void attn_kernel(
    const ushort* __restrict__ Qp, const ushort* __restrict__ Kp,
    const ushort* __restrict__ Vt, ushort* __restrict__ AO)
{
    const int wgid = (blockIdx.x & 7) * 64 + (blockIdx.x >> 3);   // 512 = 8*64
    const int g = wgid & 15;             // r-pair index
    const int h = (wgid >> 4) & 15;
    const int b = wgid >> 8;
    const int r0 = g << 1;
    const int tid  = threadIdx.x;
    const int lane = tid & 63;
    const int wave = tid >> 6;           // 0..7
    const int rw = r0 + (wave >> 2);     // this wave's r-tile

    __shared__ ushort Ks[2][4096];
    __shared__ ushort Vs[2][4096];
    __shared__ ushort QPs[8192];         // 128 rows x 64: Q (prologue) then P (wave-private rows)

    const ushort* Qb = Qp + (size_t)(b*16 + h) * 2048 * 64;
    const ushort* Kb = Kp + (size_t)(b*16 + h) * 2048 * 64;
    const ushort* Vb = Vt + (size_t)(b*16 + h) * 64 * 2048;

    // K/V per-lane pre-swizzled source offsets (1 unit per lane per tile: 512 units, 512 threads)
    const int krow = tid >> 3;
    const int kcol = (tid & 7) ^ (krow & 7);
    const int koff = krow*64   + kcol*8;
    const int voff = krow*2048 + kcol*8;

    int clo = r0 - 15; if (clo < 0) clo = 0;
    int chi = r0 + 16; if (chi > 31) chi = 31;   // r1+15

    // prologue: Q (2 r-tiles, 2 units/wave-lane) + first K/V tile
    #pragma unroll
    for (int t = 0; t < 2; ++t) {
        int u = wave*128 + t*64 + lane;
        int row = u >> 3;
        int col = (u & 7) ^ (row & 7);
        gll16(Qb + (size_t)(r0*64 + row)*64 + col*8, QPs + (wave*128 + t*64)*8);
    }
    gll16(Kb + (size_t)clo*4096 + koff, &Ks[0][wave*64*8]);
    gll16(Vb + (size_t)clo*64   + voff, &Vs[0][wave*64*8]);
    __syncthreads();   // drains vmcnt(0): Q + tile clo in LDS

    // hoist Q fragments (loop-invariant, wave-private rows)
    bfx8 qf[2];
    #pragma unroll
    for (int kk = 0; kk < 2; ++kk) {
        int arow = wave*16 + (lane & 15);
        int unit = kk*4 + (lane >> 4);
        qf[kk] = *reinterpret_cast<const bfx8*>(&QPs[arow*64 + (unit ^ (arow & 7))*8]);
    }

    f32x4 acc_o[4];
    #pragma unroll
    for (int n = 0; n < 4; ++n) acc_o[n] = (f32x4){0.f,0.f,0.f,0.f};

    const float SC = 0.125f * 1.44269504f;    // scale folded with log2(e)
    int cur = 0;
    for (int c = clo; c <= chi; ++c) {
        // prefetch next K/V into the other buffer (flies during compute)
        if (c < chi) {
            gll16(Kb + (size_t)(c+1)*4096 + koff, &Ks[cur^1][wave*64*8]);
            gll16(Vb + (size_t)(c+1)*64   + voff, &Vs[cur^1][wave*64*8]);
        }

        if (c >= rw - 15 && c <= rw + 15) {   // this wave's band (guard has no barrier)
            // QK^T: wave's 16-row strip x 64 keys
            f32x4 sc[4];
            #pragma unroll
            for (int n = 0; n < 4; ++n) sc[n] = (f32x4){0.f,0.f,0.f,0.f};
            #pragma unroll
            for (int kk = 0; kk < 2; ++kk) {
                #pragma unroll
                for (int n = 0; n < 4; ++n) {
                    int brow = n*16 + (lane & 15);
                    int unit = kk*4 + (lane >> 4);
                    bfx8 kf = *reinterpret_cast<const bfx8*>(&Ks[cur][brow*64 + (unit ^ (brow & 7))*8]);
                    sc[n] = __builtin_amdgcn_mfma_f32_16x16x32_bf16(qf[kk], kf, sc[n], 0,0,0);
                }
            }

            // per-pair softmax, no max-subtract; VALU-only DPP reduce over 16 lanes
            float pn[4][4]; float inv[4];
            #pragma unroll
            for (int i = 0; i < 4; ++i) {
                float ssum = 0.f;
                #pragma unroll
                for (int n = 0; n < 4; ++n) { float e = exp2f(sc[n][i]*SC); pn[n][i] = e; ssum += e; }
                ssum = dpp_add<0xB1>(ssum);     // quad_perm [1,0,3,2]
                ssum = dpp_add<0x4E>(ssum);     // quad_perm [2,3,0,1]
                ssum = dpp_add<0x124>(ssum);    // row_ror:4
                ssum = dpp_add<0x128>(ssum);    // row_ror:8
                inv[i] = __builtin_amdgcn_rcpf(ssum);
            }
            // write normalized P (bf16, swizzled) — wave-private rows, no barrier needed
            #pragma unroll
            for (int n = 0; n < 4; ++n)
                #pragma unroll
                for (int i = 0; i < 4; ++i) {
                    int row  = wave*16 + (lane >> 4)*4 + i;
                    int colv = n*16 + (lane & 15);
                    QPs[row*64 + ((colv >> 3) ^ (row & 7))*8 + (colv & 7)] = f2bf(pn[n][i]*inv[i]);
                }

            // O += P * V
            #pragma unroll
            for (int kk = 0; kk < 2; ++kk) {
                int arow = wave*16 + (lane & 15);
                int unit = kk*4 + (lane >> 4);
                bfx8 pf = *reinterpret_cast<const bfx8*>(&QPs[arow*64 + (unit ^ (arow & 7))*8]);
                #pragma unroll
                for (int n = 0; n < 4; ++n) {
                    int brow = n*16 + (lane & 15);   // d
                    bfx8 vf = *reinterpret_cast<const bfx8*>(&Vs[cur][brow*64 + (unit ^ (brow & 7))*8]);
                    acc_o[n] = __builtin_amdgcn_mfma_f32_16x16x32_bf16(pf, vf, acc_o[n], 0,0,0);
                }
            }
        }

        __syncthreads();   // drains vmcnt(0): prefetch landed; all reads of cur done
        cur ^= 1;
    }

    // write O strip to AO [B][S][E] (bf16 workspace), e = h*64 + d
    #pragma unroll
    for (int n = 0; n < 4; ++n)
        #pragma unroll
        for (int i = 0; i < 4; ++i) {
            int qrow = r0*64 + wave*16 + (lane >> 4)*4 + i;
            int e    = h*64 + n*16 + (lane & 15);
            AO[((size_t)b*2048 + qrow)*1024 + e] = f2bf(acc_o[n][i]);
        }
}

extern "C" void kernel_launch(void* const* d_in, const int* in_sizes, int n_in,
                              void* d_out, int out_size, void* d_ws, size_t ws_size,
                              hipStream_t stream)
{
    (void)in_sizes; (void)n_in; (void)out_size; (void)ws_size;
    const float* q  = (const float*)d_in[0];
    const float* k  = (const float*)d_in[1];
    const float* v  = (const float*)d_in[2];
    const float* wq = (const float*)d_in[3];
    const float* wk = (const float*)d_in[4];
    const float* wv = (const float*)d_in[5];
    const float* wo = (const float*)d_in[6];

    ushort* ws = (ushort*)d_ws;
    const size_t IN_E = 4096ull * 1024ull;   // 4,194,304 elems
    const size_t W_E  = 1024ull * 1024ull;   // 1,048,576 elems
    ushort* wqb = ws;                  // bf16 weights
    ushort* wkb = wqb + W_E;
    ushort* wvb = wkb + W_E;
    ushort* wob = wvb + W_E;
    ushort* Qp  = wob + W_E;           // [B][H][S][D]
    ushort* Kp  = Qp + IN_E;           // [B][H][S][D]
    ushort* Vt  = Kp + IN_E;           // [B][H][D][S]
    ushort* AO  = Vt + IN_E;           // [B][S][E]
    // total workspace: 4*W_E + 4*IN_E = 20,971,520 ushorts = 40 MiB

    cvt_w<<<1024, 256, 0, stream>>>(wq, wk, wv, wo, ws);
    proj_kernel<<<768, 256, 0, stream>>>(q, k, v, wqb, wkb, wvb, Qp, Kp, Vt);
    attn_kernel<<<512, 512, 0, stream>>>(Qp, Kp, Vt, AO);
    outproj_kernel<<<256, 256, 0, stream>>>(AO, wob, (float*)d_out);
}

// Round 10
// 248.851 us; speedup vs baseline: 1.0635x; 1.0120x over previous
//
#include <hip/hip_runtime.h>
#include <hip/hip_bf16.h>

typedef __attribute__((ext_vector_type(4))) float f32x4;
typedef __attribute__((ext_vector_type(8))) short bfx8;   // 8 bf16 = 4 VGPRs (MFMA A/B frag)

#define K_DIM 1024
#define N_DIM 1024

__device__ __forceinline__ ushort f2bf(float f) {
    uint u = __float_as_uint(f);
    u += 0x7fffu + ((u >> 16) & 1u);     // round-to-nearest-even
    return (ushort)(u >> 16);
}

// pack 2 f32 -> 1 uint of 2 bf16 (hardware cvt path); memcpy reinterpret
// (bit_cast rejects __hip_bfloat162: not trivially copyable)
__device__ __forceinline__ uint pk2bf(float lo, float hi) {
    __hip_bfloat162 h = __float22bfloat162_rn(float2{lo, hi});
    uint r;
    __builtin_memcpy(&r, &h, 4);
    return r;
}

// async global->LDS, 16B per lane. LDS dest must be wave-uniform base (lane*16 implicit).
__device__ __forceinline__ void gll16(const ushort* g, ushort* l) {
    __builtin_amdgcn_global_load_lds(
        (const __attribute__((address_space(1))) uint*)g,
        (__attribute__((address_space(3))) uint*)l,
        16, 0, 0);
}

// VALU-only reduce step: x + dpp_perm(x). CTRL compile-time constant:
// 0xB1=quad_perm[1,0,3,2](xor1), 0x4E=quad_perm[2,3,0,1](xor2),
// 0x124=row_ror:4, 0x128=row_ror:8 (row = 16 lanes).
template<int CTRL>
__device__ __forceinline__ float dpp_add(float x) {
    int yi = __builtin_amdgcn_update_dpp(0, __float_as_int(x), CTRL, 0xf, 0xf, true);
    return x + __int_as_float(yi);
}

// per-lane byte offset of the MFMA A/B fragment inside a swizzled 64-row tile:
// elem addr = brow*128B + ((kk*4+(lane>>4)) ^ (lane&7))*16B with brow = n*16+(lane&15);
// the n*2048 part becomes a ds_read immediate offset at the call site.
__device__ __forceinline__ int frag_off(int lane, int kk) {
    return (lane & 15)*128 + (((kk<<2) + (lane >> 4)) ^ (lane & 7))*16;
}

// ---------------- f32 -> bf16 conversion of the 4 weights ----------------
__global__ __launch_bounds__(256) void cvt_w(
    const float* __restrict__ wq, const float* __restrict__ wk,
    const float* __restrict__ wv, const float* __restrict__ wo,
    ushort* __restrict__ ws)
{
    const int W4 = 1 << 18;   // 1024*1024/4 float4 units per weight
    const int total = 4*W4;
    ushort4* dst4 = reinterpret_cast<ushort4*>(ws);
    for (int u = blockIdx.x*blockDim.x + threadIdx.x; u < total; u += gridDim.x*blockDim.x) {
        int op = u >> 18;
        int local = u & (W4-1);
        const float* src = op==0 ? wq : (op==1 ? wk : (op==2 ? wv : wo));
        float4 f = reinterpret_cast<const float4*>(src)[local];
        ushort4 o;
        o.x = f2bf(f.x); o.y = f2bf(f.y); o.z = f2bf(f.z); o.w = f2bf(f.w);
        dst4[u] = o;
    }
}

// ---------------- GEMM body: C[m][n] = sum_k A[m][k] * W[n][k] ----
// 128x128 tile, BK=64, 4 waves (2x2 of 64x64), 16x16x32 bf16 MFMA.
// B (weights) staged via global_load_lds w16 with pre-swizzled source.
// MODE 0/1: A is f32 global (inputs), converted to bf16 (cvt_pk) during reg-staging.
// MODE 2:   A is bf16 (AO), staged via global_load_lds.
// MODE 0: out bf16 [B][H][S][D]   (Q/K projection)
// MODE 1: out bf16 [B][H][D][S]   (V projection, transposed for PV reads)
// MODE 2: out f32  [M][N]         (final output -> d_out, reference dtype f32)
template<int MODE>
__device__ __forceinline__ void gemm_body(
    const float* __restrict__ Af, const ushort* __restrict__ Ab,
    const ushort* __restrict__ Bw,
    ushort* __restrict__ C, float* __restrict__ Cf,
    int blk, ushort* As, ushort* Bs)
{
    const int tid  = threadIdx.x;
    const int lane = tid & 63;
    const int wave = tid >> 6;
    const int tn = blk & 7;     // N/128 = 8
    const int tm = blk >> 3;    // M/128 = 32
    const int wr = wave >> 1, wc = wave & 1;

    // per-lane pre-swizzled source offsets for gll staging (4 x 16B units per tile)
    int goff[4];
    #pragma unroll
    for (int t = 0; t < 4; ++t) {
        int u = wave*256 + t*64 + lane;          // 1024 units per 128x64 tile
        int row = u >> 3;
        int col = (u & 7) ^ (row & 7);           // inverse swizzle on source
        goff[t] = row * K_DIM + col * 8;
    }
    const int fo0 = frag_off(lane, 0), fo1 = frag_off(lane, 1);
    const ushort* Bbase  = Bw + (size_t)tn * 128 * K_DIM;
    const float*  Afbase = (MODE < 2) ? Af + (size_t)tm * 128 * K_DIM : nullptr;
    const ushort* Abbase = (MODE == 2) ? Ab + (size_t)tm * 128 * K_DIM : nullptr;

    f32x4 acc[4][4];
    #pragma unroll
    for (int a = 0; a < 4; ++a)
        #pragma unroll
        for (int b2 = 0; b2 < 4; ++b2)
            acc[a][b2] = (f32x4){0.f, 0.f, 0.f, 0.f};

    for (int k0 = 0; k0 < K_DIM; k0 += 64) {
        __syncthreads();   // prior compute done reading LDS
        #pragma unroll
        for (int t = 0; t < 4; ++t)
            gll16(Bbase + k0 + goff[t], Bs + (wave*256 + t*64)*8);
        if constexpr (MODE == 2) {
            #pragma unroll
            for (int t = 0; t < 4; ++t)
                gll16(Abbase + k0 + goff[t], As + (wave*256 + t*64)*8);
        } else {
            // reg-staged A with fused f32->bf16 (cvt_pk), one 16B swizzled ds_write
            #pragma unroll
            for (int t = 0; t < 4; ++t) {
                int u = tid + t*256;
                int row = u >> 3, col = u & 7;
                const float* s = Afbase + (size_t)row*K_DIM + k0 + col*8;
                float4 f0 = *reinterpret_cast<const float4*>(s);
                float4 f1 = *reinterpret_cast<const float4*>(s + 4);
                uint4 packed;
                packed.x = pk2bf(f0.x, f0.y);
                packed.y = pk2bf(f0.z, f0.w);
                packed.z = pk2bf(f1.x, f1.y);
                packed.w = pk2bf(f1.z, f1.w);
                *reinterpret_cast<uint4*>(&As[row*64 + (col ^ (row & 7))*8]) = packed;
            }
        }
        __syncthreads();   // drains vmcnt+lgkm -> tiles ready
        #pragma unroll
        for (int kk = 0; kk < 2; ++kk) {
            const int fo = kk ? fo1 : fo0;
            const char* ap = (const char*)As + wr*8192 + fo;
            const char* bp = (const char*)Bs + wc*8192 + fo;
            bfx8 af[4], bfr[4];
            #pragma unroll
            for (int mi = 0; mi < 4; ++mi)
                af[mi] = *reinterpret_cast<const bfx8*>(ap + mi*2048);
            #pragma unroll
            for (int ni = 0; ni < 4; ++ni)
                bfr[ni] = *reinterpret_cast<const bfx8*>(bp + ni*2048);
            #pragma unroll
            for (int mi = 0; mi < 4; ++mi)
                #pragma unroll
                for (int ni = 0; ni < 4; ++ni)
                    acc[mi][ni] = __builtin_amdgcn_mfma_f32_16x16x32_bf16(af[mi], bfr[ni], acc[mi][ni], 0, 0, 0);
        }
    }
    // epilogue: D layout col = lane&15, row = (lane>>4)*4 + i
    #pragma unroll
    for (int mi = 0; mi < 4; ++mi)
      #pragma unroll
      for (int ni = 0; ni < 4; ++ni)
        #pragma unroll
        for (int i = 0; i < 4; ++i) {
            int gr = tm*128 + wr*64 + mi*16 + (lane >> 4)*4 + i;   // m: b*2048+s
            int gc = tn*128 + wc*64 + ni*16 + (lane & 15);         // n: h*64+d
            if constexpr (MODE == 0) {
                int b = gr >> 11, s = gr & 2047, h = gc >> 6, d = gc & 63;
                C[(((size_t)(b*16 + h))*2048 + s)*64 + d] = f2bf(acc[mi][ni][i]);
            } else if constexpr (MODE == 1) {
                int b = gr >> 11, s = gr & 2047, h = gc >> 6, d = gc & 63;
                C[(((size_t)(b*16 + h))*64 + d)*2048 + s] = f2bf(acc[mi][ni][i]);
            } else {
                Cf[(size_t)gr*N_DIM + gc] = acc[mi][ni][i];
            }
        }
}

// 1D grid 768 = 3 ops x 256 tiles; XCD swizzle: 96 consecutive wgid per XCD so
// the 8 tn-blocks sharing an A-panel hit the same XCD's L2.
__global__ __launch_bounds__(256) void proj_kernel(
    const float* __restrict__ q, const float* __restrict__ k, const float* __restrict__ v,
    const ushort* __restrict__ wqb, const ushort* __restrict__ wkb, const ushort* __restrict__ wvb,
    ushort* __restrict__ Qp, ushort* __restrict__ Kp, ushort* __restrict__ Vt)
{
    __shared__ ushort As[128*64];
    __shared__ ushort Bs[128*64];
    int wgid = (blockIdx.x & 7) * 96 + (blockIdx.x >> 3);   // 768 = 8*96, bijective
    int op = wgid >> 8;
    int t  = wgid & 255;
    if (op == 0)      gemm_body<0>(q, nullptr, wqb, Qp, nullptr, t, As, Bs);
    else if (op == 1) gemm_body<0>(k, nullptr, wkb, Kp, nullptr, t, As, Bs);
    else              gemm_body<1>(v, nullptr, wvb, Vt, nullptr, t, As, Bs);
}

__global__ __launch_bounds__(256) void outproj_kernel(
    const ushort* __restrict__ AO, const ushort* __restrict__ wob, float* __restrict__ out)
{
    __shared__ ushort As[128*64];
    __shared__ ushort Bs[128*64];
    int wgid = (blockIdx.x & 7) * 32 + (blockIdx.x >> 3);   // 256 = 8*32, bijective
    gemm_body<2>(nullptr, AO, wob, nullptr, out, wgid, As, Bs);
}

// ---------------- block-sparse attention ----------------
// grid: b(2)*h(16)*rpair(16) = 512 blocks, 512 threads (8 waves).
// XCD swizzle: 64 consecutive wgid per XCD = 4 full (b,h) groups -> K/V (1MB)
// resident in that XCD's L2 across its 16 r-pair blocks.
// Waves 0-3 own r0's 16-row strips, waves 4-7 own r1's. One c-band union
// [r0-15, r1+15] (<=33 tiles) serves both r's. Double-buffered K/V via
// global_load_lds; Q/P share one wave-private buffer; one barrier per phase;
// per-pair softmax with DPP rotate-reduce; imm-offset frag reads; setprio on MFMA.
__global__ __launch_bounds__(512) void attn_kernel(
    const ushort* __restrict__ Qp, const ushort* __restrict__ Kp,
    const ushort* __restrict__ Vt, ushort* __restrict__ AO)
{
    const int wgid = (blockIdx.x & 7) * 64 + (blockIdx.x >> 3);   // 512 = 8*64
    const int g = wgid & 15;             // r-pair index
    const int h = (wgid >> 4) & 15;
    const int b = wgid >> 8;
    const int r0 = g << 1;
    const int tid  = threadIdx.x;
    const int lane = tid & 63;
    const int wave = tid >> 6;           // 0..7
    const int rw = r0 + (wave >> 2);     // this wave's r-tile

    __shared__ ushort Ks[2][4096];
    __shared__ ushort Vs[2][4096];
    __shared__ ushort QPs[8192];         // 128 rows x 64: Q (prologue) then P (wave-private rows)

    const ushort* Qb = Qp + (size_t)(b*16 + h) * 2048 * 64;
    const ushort* Kb = Kp + (size_t)(b*16 + h) * 2048 * 64;
    const ushort* Vb = Vt + (size_t)(b*16 + h) * 64 * 2048;

    // K/V per-lane pre-swizzled source offsets (1 unit per lane per tile: 512 units, 512 threads)
    const int krow = tid >> 3;
    const int kcol = (tid & 7) ^ (krow & 7);
    const int koff = krow*64   + kcol*8;
    const int voff = krow*2048 + kcol*8;
    const int fo0 = frag_off(lane, 0), fo1 = frag_off(lane, 1);

    int clo = r0 - 15; if (clo < 0) clo = 0;
    int chi = r0 + 16; if (chi > 31) chi = 31;   // r1+15

    // prologue: Q (2 r-tiles, 2 units/wave-lane) + first K/V tile
    #pragma unroll
    for (int t = 0; t < 2; ++t) {
        int u = wave*128 + t*64 + lane;
        int row = u >> 3;
        int col = (u & 7) ^ (row & 7);
        gll16(Qb + (size_t)(r0*64 + row)*64 + col*8, QPs + (wave*128 + t*64)*8);
    }
    gll16(Kb + (size_t)clo*4096 + koff, &Ks[0][wave*64*8]);
    gll16(Vb + (size_t)clo*64   + voff, &Vs[0][wave*64*8]);
    __syncthreads();   // drains vmcnt(0): Q + tile clo in LDS

    // hoist Q fragments (loop-invariant, wave-private rows)
    const char* qp_base = (const char*)QPs + wave*2048;
    bfx8 qf[2];
    qf[0] = *reinterpret_cast<const bfx8*>(qp_base + fo0);
    qf[1] = *reinterpret_cast<const bfx8*>(qp_base + fo1);

    f32x4 acc_o[4];
    #pragma unroll
    for (int n = 0; n < 4; ++n) acc_o[n] = (f32x4){0.f,0.f,0.f,0.f};

    const float SC = 0.125f * 1.44269504f;    // scale folded with log2(e)
    int cur = 0;
    for (int c = clo; c <= chi; ++c) {
        // prefetch next K/V into the other buffer (flies during compute)
        if (c < chi) {
            gll16(Kb + (size_t)(c+1)*4096 + koff, &Ks[cur^1][wave*64*8]);
            gll16(Vb + (size_t)(c+1)*64   + voff, &Vs[cur^1][wave*64*8]);
        }

        if (c >= rw - 15 && c <= rw + 15) {   // this wave's band (guard has no barrier)
            // QK^T: wave's 16-row strip x 64 keys (imm-offset frag reads)
            const char* kcur = (const char*)&Ks[cur][0];
            f32x4 sc[4];
            #pragma unroll
            for (int n = 0; n < 4; ++n) sc[n] = (f32x4){0.f,0.f,0.f,0.f};
            #pragma unroll
            for (int kk = 0; kk < 2; ++kk) {
                const char* kp = kcur + (kk ? fo1 : fo0);
                bfx8 kf[4];
                #pragma unroll
                for (int n = 0; n < 4; ++n)
                    kf[n] = *reinterpret_cast<const bfx8*>(kp + n*2048);
                __builtin_amdgcn_s_setprio(1);
                #pragma unroll
                for (int n = 0; n < 4; ++n)
                    sc[n] = __builtin_amdgcn_mfma_f32_16x16x32_bf16(qf[kk], kf[n], sc[n], 0,0,0);
                __builtin_amdgcn_s_setprio(0);
            }

            // per-pair softmax, no max-subtract; VALU-only DPP reduce over 16 lanes
            float pn[4][4]; float inv[4];
            #pragma unroll
            for (int i = 0; i < 4; ++i) {
                float ssum = 0.f;
                #pragma unroll
                for (int n = 0; n < 4; ++n) { float e = exp2f(sc[n][i]*SC); pn[n][i] = e; ssum += e; }
                ssum = dpp_add<0xB1>(ssum);     // quad_perm [1,0,3,2]
                ssum = dpp_add<0x4E>(ssum);     // quad_perm [2,3,0,1]
                ssum = dpp_add<0x124>(ssum);    // row_ror:4
                ssum = dpp_add<0x128>(ssum);    // row_ror:8
                inv[i] = __builtin_amdgcn_rcpf(ssum);
            }
            // write normalized P (bf16, swizzled) — wave-private rows, no barrier.
            // cvt_pk pairs rows (2ip, 2ip+1): one pack, two b16 writes.
            #pragma unroll
            for (int n = 0; n < 4; ++n) {
                int colv = n*16 + (lane & 15);
                #pragma unroll
                for (int ip = 0; ip < 2; ++ip) {
                    uint w = pk2bf(pn[n][2*ip]*inv[2*ip], pn[n][2*ip+1]*inv[2*ip+1]);
                    int row0 = wave*16 + (lane >> 4)*4 + 2*ip;
                    QPs[row0*64     + ((colv >> 3) ^ ( row0    & 7))*8 + (colv & 7)] = (ushort)w;
                    QPs[(row0+1)*64 + ((colv >> 3) ^ ((row0+1) & 7))*8 + (colv & 7)] = (ushort)(w >> 16);
                }
            }

            // O += P * V  (imm-offset frag reads)
            const char* vcur = (const char*)&Vs[cur][0];
            #pragma unroll
            for (int kk = 0; kk < 2; ++kk) {
                const int fo = kk ? fo1 : fo0;
                bfx8 pf = *reinterpret_cast<const bfx8*>(qp_base + fo);
                const char* vp = vcur + fo;
                bfx8 vf[4];
                #pragma unroll
                for (int n = 0; n < 4; ++n)
                    vf[n] = *reinterpret_cast<const bfx8*>(vp + n*2048);
                __builtin_amdgcn_s_setprio(1);
                #pragma unroll
                for (int n = 0; n < 4; ++n)
                    acc_o[n] = __builtin_amdgcn_mfma_f32_16x16x32_bf16(pf, vf[n], acc_o[n], 0,0,0);
                __builtin_amdgcn_s_setprio(0);
            }
        }

        __syncthreads();   // drains vmcnt(0): prefetch landed; all reads of cur done
        cur ^= 1;
    }

    // write O strip to AO [B][S][E] (bf16 workspace), e = h*64 + d
    #pragma unroll
    for (int n = 0; n < 4; ++n)
        #pragma unroll
        for (int i = 0; i < 4; ++i) {
            int qrow = r0*64 + wave*16 + (lane >> 4)*4 + i;
            int e    = h*64 + n*16 + (lane & 15);
            AO[((size_t)b*2048 + qrow)*1024 + e] = f2bf(acc_o[n][i]);
        }
}

extern "C" void kernel_launch(void* const* d_in, const int* in_sizes, int n_in,
                              void* d_out, int out_size, void* d_ws, size_t ws_size,
                              hipStream_t stream)
{
    (void)in_sizes; (void)n_in; (void)out_size; (void)ws_size;
    const float* q  = (const float*)d_in[0];
    const float* k  = (const float*)d_in[1];
    const float* v  = (const float*)d_in[2];
    const float* wq = (const float*)d_in[3];
    const float* wk = (const float*)d_in[4];
    const float* wv = (const float*)d_in[5];
    const float* wo = (const float*)d_in[6];

    ushort* ws = (ushort*)d_ws;
    const size_t IN_E = 4096ull * 1024ull;   // 4,194,304 elems
    const size_t W_E  = 1024ull * 1024ull;   // 1,048,576 elems
    ushort* wqb = ws;                  // bf16 weights
    ushort* wkb = wqb + W_E;
    ushort* wvb = wkb + W_E;
    ushort* wob = wvb + W_E;
    ushort* Qp  = wob + W_E;           // [B][H][S][D]
    ushort* Kp  = Qp + IN_E;           // [B][H][S][D]
    ushort* Vt  = Kp + IN_E;           // [B][H][D][S]
    ushort* AO  = Vt + IN_E;           // [B][S][E]
    // total workspace: 4*W_E + 4*IN_E = 20,971,520 ushorts = 40 MiB

    cvt_w<<<1024, 256, 0, stream>>>(wq, wk, wv, wo, ws);
    proj_kernel<<<768, 256, 0, stream>>>(q, k, v, wqb, wkb, wvb, Qp, Kp, Vt);
    attn_kernel<<<512, 512, 0, stream>>>(Qp, Kp, Vt, AO);
    outproj_kernel<<<256, 256, 0, stream>>>(AO, wob, (float*)d_out);
}